// Round 14
// baseline (4338.420 us; speedup 1.0000x reference)
//
#include <hip/hip_runtime.h>
#include <cstdint>
#include <cstddef>

#define B_ 512
#define S_ 336
#define F_ 16
#define H_ 256
#define P_ 48

typedef __bf16 bhalf;
typedef __attribute__((ext_vector_type(8))) __bf16 bhalf8;
typedef __attribute__((ext_vector_type(4))) float f32x4;

#define MFMA16(A, Bv, C) __builtin_amdgcn_mfma_f32_16x16x32_bf16((A), (Bv), (C), 0, 0, 0)

__device__ __forceinline__ float fastrcp(float x) { return __builtin_amdgcn_rcpf(x); }
__device__ __forceinline__ float sigm(float x) { return fastrcp(1.0f + __expf(-x)); }
__device__ __forceinline__ float tanh_f(float x) { return 2.0f * fastrcp(1.0f + __expf(-2.0f * x)) - 1.0f; }

__device__ __forceinline__ bhalf u16_to_bf(unsigned int u) {
  return __builtin_bit_cast(__bf16, (unsigned short)u);
}
__device__ __forceinline__ unsigned short bf_to_u16(bhalf b) {
  return __builtin_bit_cast(unsigned short, b);
}

__device__ __forceinline__ bhalf8 bzero8() {
  bhalf8 v;
#pragma unroll
  for (int j = 0; j < 8; ++j) v[j] = (bhalf)0.0f;
  return v;
}

// ---------------------------------------------------------------------------
// Encoder: weight-stationary MFMA flag pipeline (r8 verified BEST; UNCHANGED).
// ---------------------------------------------------------------------------
__global__ __launch_bounds__(128, 1) void enc_kernel(
    const float* __restrict__ Whh, const float* __restrict__ Wih,
    const float* __restrict__ bih, const float* __restrict__ bhh,
    const float* __restrict__ xb,        // [B][S][F] fp32
    bhalf* __restrict__ enc_out,         // [B][S][H]
    float* __restrict__ hcur,            // [B][H] final h, fp32 exact
    unsigned int* __restrict__ hpack,    // [2][B][H] relaxed-atomic channel
    unsigned int* __restrict__ flags)    // [32][8] steps-completed counters
{
  const int tid  = threadIdx.x;
  const int lane = tid & 63;
  const int wv   = tid >> 6;
  const int ncol = lane & 15;
  const int quad = lane >> 4;

  const int blk = blockIdx.x;
  const int g   = (blk & 7) * 4 + (blk >> 6);   // group 0..31 (members share XCD)
  const int w   = (blk >> 3) & 7;               // member 0..7
  const int b0  = g * 16;
  const int iw0 = w * 32;
  const int i0  = iw0 + wv * 16;

  bhalf8 bWh[3][9], bWl[3][9];
#pragma unroll
  for (int gg = 0; gg < 3; ++gg) {
    const int jrow = gg * 256 + i0 + ncol;
#pragma unroll
    for (int kt = 0; kt < 9; ++kt) {
      bhalf8 vh = bzero8(), vl = bzero8();
      if (kt < 8) {
        const float* src = Whh + (size_t)jrow * 256 + kt * 32 + quad * 8;
#pragma unroll
        for (int j = 0; j < 8; ++j) {
          const float v = src[j];
          const bhalf h = (bhalf)v;
          vh[j] = h;
          vl[j] = (bhalf)(v - (float)h);
        }
      } else if (quad < 2) {
        const float* src = Wih + (size_t)jrow * 16 + quad * 8;
#pragma unroll
        for (int j = 0; j < 8; ++j) {
          const float v = src[j];
          const bhalf h = (bhalf)v;
          vh[j] = h;
          vl[j] = (bhalf)(v - (float)h);
        }
      }
      bWh[gg][kt] = vh;
      bWl[gg][kt] = vl;
    }
  }

  const int jr = i0 + ncol;
  const float bR  = bih[jr]       + bhh[jr];
  const float bZ  = bih[256 + jr] + bhh[256 + jr];
  const float bNx = bih[512 + jr];
  const float bNh = bhh[512 + jr];

  const int bA = b0 + ncol;
  const int kA = quad * 8;

  float hold[4] = {0.0f, 0.0f, 0.0f, 0.0f};

  for (int t = 0; t < S_; ++t) {
    bhalf8 xh = bzero8(), xl = bzero8();
    if (quad < 2) {
      const float* xp = xb + ((size_t)bA * S_ + t) * F_ + quad * 8;
#pragma unroll
      for (int j = 0; j < 8; ++j) {
        const float v = __builtin_nontemporal_load(xp + j);
        const bhalf h = (bhalf)v;
        xh[j] = h;
        xl[j] = (bhalf)(v - (float)h);
      }
    }

    f32x4 aR0 = {0,0,0,0}, aR1 = {0,0,0,0}, aR2 = {0,0,0,0};
    f32x4 aZ0 = {0,0,0,0}, aZ1 = {0,0,0,0}, aZ2 = {0,0,0,0};
    f32x4 aN0 = {0,0,0,0}, aN1 = {0,0,0,0}, aN2 = {0,0,0,0};
    f32x4 aNx = {0,0,0,0};

    // kt = 8: x-part (h-independent -> BEFORE the spin)
    aR0 = MFMA16(xh, bWh[0][8], aR0);
    aR1 = MFMA16(xh, bWl[0][8], aR1);
    aR2 = MFMA16(xl, bWh[0][8], aR2);
    aZ0 = MFMA16(xh, bWh[1][8], aZ0);
    aZ1 = MFMA16(xh, bWl[1][8], aZ1);
    aZ2 = MFMA16(xl, bWh[1][8], aZ2);
    aNx = MFMA16(xh, bWh[2][8], aNx);
    aNx = MFMA16(xh, bWl[2][8], aNx);
    aNx = MFMA16(xl, bWh[2][8], aNx);

    if (t > 0) {
      const unsigned int* fp = &flags[g * 8 + (lane & 7)];
      while (__hip_atomic_load(fp, __ATOMIC_RELAXED, __HIP_MEMORY_SCOPE_AGENT) <
             (unsigned int)t)
        __builtin_amdgcn_s_sleep(1);

      const int slot = (t - 1) & 1;
      const unsigned long long* hp64 =
          (const unsigned long long*)(hpack + ((size_t)slot * B_ + bA) * H_ + kA);

      unsigned long long wbuf[32];
#pragma unroll
      for (int i = 0; i < 32; ++i)
        wbuf[i] = __hip_atomic_load(hp64 + (i >> 2) * 16 + (i & 3),
                                    __ATOMIC_RELAXED, __HIP_MEMORY_SCOPE_AGENT);

#pragma unroll
      for (int kt = 0; kt < 8; ++kt) {
        bhalf8 Ah, Al;
#pragma unroll
        for (int j2 = 0; j2 < 4; ++j2) {
          const unsigned long long w2 = wbuf[kt * 4 + j2];
          Ah[2 * j2]     = u16_to_bf((unsigned int)w2);
          Al[2 * j2]     = u16_to_bf((unsigned int)(w2 >> 16));
          Ah[2 * j2 + 1] = u16_to_bf((unsigned int)(w2 >> 32));
          Al[2 * j2 + 1] = u16_to_bf((unsigned int)(w2 >> 48));
        }
        aR0 = MFMA16(Ah, bWh[0][kt], aR0);
        aR1 = MFMA16(Ah, bWl[0][kt], aR1);
        aR2 = MFMA16(Al, bWh[0][kt], aR2);
        aZ0 = MFMA16(Ah, bWh[1][kt], aZ0);
        aZ1 = MFMA16(Ah, bWl[1][kt], aZ1);
        aZ2 = MFMA16(Al, bWh[1][kt], aZ2);
        aN0 = MFMA16(Ah, bWh[2][kt], aN0);
        aN1 = MFMA16(Ah, bWl[2][kt], aN1);
        aN2 = MFMA16(Al, bWh[2][kt], aN2);
      }
    }

    const int iL = i0 + ncol;
    bhalf his[4];
#pragma unroll
    for (int r = 0; r < 4; ++r) {
      const float sR  = aR0[r] + aR1[r] + aR2[r] + bR;
      const float sZ  = aZ0[r] + aZ1[r] + aZ2[r] + bZ;
      const float nhv = aN0[r] + aN1[r] + aN2[r] + bNh;
      const float nxv = aNx[r] + bNx;
      const float rr = sigm(sR);
      const float zz = sigm(sZ);
      const float nn = tanh_f(nxv + rr * nhv);
      const float h2 = (1.0f - zz) * nn + zz * hold[r];
      hold[r] = h2;
      his[r] = (bhalf)h2;
      const bhalf lo = (bhalf)(h2 - (float)his[r]);
      const int bb = b0 + quad * 4 + r;
      const unsigned int wrd =
          (unsigned int)bf_to_u16(his[r]) | ((unsigned int)bf_to_u16(lo) << 16);
      __hip_atomic_store(&hpack[((size_t)(t & 1) * B_ + bb) * H_ + iL], wrd,
                         __ATOMIC_RELAXED, __HIP_MEMORY_SCOPE_AGENT);
    }

    __syncthreads();
    if (tid == 0) {
      __hip_atomic_store(&flags[g * 8 + w], (unsigned int)(t + 1),
                         __ATOMIC_RELAXED, __HIP_MEMORY_SCOPE_AGENT);
    }

#pragma unroll
    for (int r = 0; r < 4; ++r) {
      const int bb = b0 + quad * 4 + r;
      __builtin_nontemporal_store(his[r], enc_out + ((size_t)bb * S_ + t) * H_ + iL);
    }
  }

#pragma unroll
  for (int r = 0; r < 4; ++r)
    hcur[(size_t)(b0 + quad * 4 + r) * H_ + i0 + ncol] = hold[r];
}

// ---------------------------------------------------------------------------
// Prep: dec GRU weights -> TRANSPOSED bf16 pack wbT[64][768][8]
// ---------------------------------------------------------------------------
__global__ __launch_bounds__(256) void wpack_kernel(const float* __restrict__ Whh,
                                                    const float* __restrict__ Wih,
                                                    bhalf* __restrict__ wbT) {
  const int idx = blockIdx.x * 256 + threadIdx.x;
  if (idx >= 64 * 768 * 8) return;
  const int j = idx & 7;
  const int row = (idx >> 3) % 768;
  const int k8 = idx / (768 * 8);
  const int k = k8 * 8 + j;
  const float v = (k < 256) ? Whh[(size_t)row * 256 + k]
                            : Wih[(size_t)row * 256 + (k - 256)];
  wbT[idx] = (bhalf)v;
}

// ---------------------------------------------------------------------------
// Prep: attW -> bf16 TRANSPOSED pack abT[36][336][8] (zero-padded k>=272)
// ---------------------------------------------------------------------------
__global__ __launch_bounds__(256) void apack_kernel(const float* __restrict__ attW,
                                                    bhalf* __restrict__ abT) {
  const int idx = blockIdx.x * 256 + threadIdx.x;
  if (idx >= 36 * 336 * 8) return;
  const int j = idx & 7;
  const int s = (idx >> 3) % 336;
  const int k8 = idx / (8 * 336);
  const int k = k8 * 8 + j;
  abT[idx] = (k < 272) ? (bhalf)attW[(size_t)s * 272 + k] : (bhalf)0.0f;
}

// ---------------------------------------------------------------------------
// Decoder v8 = r13's v7 + ONE change: the 26 combine global rows per thread
// are CONSTANT across all 48 steps (enc_out immutable during dec) -> loaded
// ONCE into 26 bhalf8 registers (104 VGPR, statically indexed) before the
// p-loop. Per-step combine = 16 LDS rows + 26 register FMAs; the per-step
// L3 long-pole and ~6.8MB/step/XCD of traffic are gone.
// Abort signature if regalloc spills: VGPR=256 + WRITE_SIZE inflation.
// ---------------------------------------------------------------------------
__global__ __launch_bounds__(256) void dec_kernel(
    const bhalf* __restrict__ wbT,      // [64][768][8]
    const bhalf* __restrict__ abT,      // [36][336][8]
    const float* __restrict__ attb,
    const float* __restrict__ bih, const float* __restrict__ bhh,
    const float* __restrict__ outW, const float* __restrict__ outb,
    const float* __restrict__ linW, const float* __restrict__ linb,
    const bhalf* __restrict__ enc_out, const float* __restrict__ hcur,
    const float* __restrict__ xb, float* __restrict__ dout)
{
  __shared__ __align__(16) bhalf encL[128 * 256];   // 65536 B: s<128 cache
  __shared__ __align__(16) float hybuf[2][288];     // ping-pong [h|y|pad]
  __shared__ __align__(16) float cL[256];
  __shared__ float sc[S_];
  __shared__ float pC[8][32][9];    // combine partials, padded (bank-safe)
  __shared__ float red[8];
  const int tid  = threadIdx.x;
  const int lane = tid & 63;
  const int wv   = tid >> 6;
  const int b    = blockIdx.x;
  const int jj   = tid;
  const int cg   = tid & 31;        // combine col-group (8 cols)
  const int ck   = tid >> 5;        // combine chunk: 16 LDS rows + 26 reg rows
  const int s2ok = tid < 80;        // handles second score row s=tid+256
  const int f_o  = tid >> 4;        // out-phase f
  const int q_o  = tid & 15;        // out-phase k-chunk

  // one-time: cache enc_out rows [0,128) (coalesced 16B)
  {
    const bhalf8* src = (const bhalf8*)(enc_out + (size_t)b * S_ * H_);
    bhalf8* dst = (bhalf8*)encL;
    for (int it = tid; it < 128 * 32; it += 256) dst[it] = src[it];
  }

  // one-time: this thread's 26 constant combine rows -> registers
  bhalf8 ebr[26];
  {
    const bhalf* epC = enc_out + ((size_t)b * S_ + 128 + ck * 26) * H_ + cg * 8;
#pragma unroll
    for (int s5 = 0; s5 < 26; ++s5)
      ebr[s5] = *(const bhalf8*)(epC + (size_t)s5 * H_);
  }

  hybuf[0][tid] = hcur[(size_t)b * H_ + tid];
  if (tid < 16) {
    hybuf[0][256 + tid] = xb[((size_t)b * S_ + (S_ - 1)) * F_ + tid];
    hybuf[1][256 + tid] = 0.0f;
  } else if (tid < 32) {
    hybuf[0][256 + tid] = 0.0f;
    hybuf[1][256 + tid] = 0.0f;
  }

  const float bRv  = bih[jj]       + bhh[jj];
  const float bZv  = bih[256 + jj] + bhh[256 + jj];
  const float bNxv = bih[512 + jj];
  const float bNhv = bhh[512 + jj];

  const float ab1 = attb[tid];
  const float ab2 = s2ok ? attb[tid + 256] : 0.0f;

  f32x4 ow[4];
  {
    const float* wrp = outW + (size_t)f_o * H_ + q_o * 16;
#pragma unroll
    for (int jv = 0; jv < 4; ++jv) ow[jv] = *(const f32x4*)(wrp + jv * 4);
  }
  const float outb_f = outb[f_o];
  const float linw_t = (tid < 16) ? linW[tid] : 0.0f;
  const float linb0  = linb[0];

  const bhalf* epL = encL + (size_t)(ck * 16) * H_ + cg * 8;   // 16 LDS rows
  __syncthreads();

  for (int p = 0; p < P_; ++p) {
    float* hc = hybuf[p & 1];          // current h|y (read)
    float* hn = hybuf[(p & 1) ^ 1];    // next h|y (write)

    // ---- scores: registers only ----
    float v1, v2 = -3.0e38f;
    {
      float d0 = 0, d1 = 0, d2 = 0, d3 = 0;
#pragma unroll 4
      for (int k8 = 0; k8 < 36; ++k8) {
        const bhalf8 q = *(const bhalf8*)(abT + ((size_t)k8 * S_ + tid) * 8);
        const float* v = hc + k8 * 8;
        d0 += (float)q[0] * v[0] + (float)q[4] * v[4];
        d1 += (float)q[1] * v[1] + (float)q[5] * v[5];
        d2 += (float)q[2] * v[2] + (float)q[6] * v[6];
        d3 += (float)q[3] * v[3] + (float)q[7] * v[7];
      }
      v1 = d0 + d1 + d2 + d3 + ab1;
    }
    if (s2ok) {
      float d0 = 0, d1 = 0, d2 = 0, d3 = 0;
#pragma unroll 4
      for (int k8 = 0; k8 < 36; ++k8) {
        const bhalf8 q = *(const bhalf8*)(abT + ((size_t)k8 * S_ + tid + 256) * 8);
        const float* v = hc + k8 * 8;
        d0 += (float)q[0] * v[0] + (float)q[4] * v[4];
        d1 += (float)q[1] * v[1] + (float)q[5] * v[5];
        d2 += (float)q[2] * v[2] + (float)q[6] * v[6];
        d3 += (float)q[3] * v[3] + (float)q[7] * v[7];
      }
      v2 = d0 + d1 + d2 + d3 + ab2;
    }

    // ---- softmax: max/sum reduces; exp stored UNNORMALIZED ----
    float m = fmaxf(v1, v2);
#pragma unroll
    for (int o = 32; o > 0; o >>= 1) m = fmaxf(m, __shfl_xor(m, o, 64));
    if (lane == 0) red[wv] = m;
    __syncthreads();                                        // (1)
    const float mx = fmaxf(fmaxf(red[0], red[1]), fmaxf(red[2], red[3]));
    const float e1 = __expf(v1 - mx);
    sc[tid] = e1;
    float e2 = 0.0f;
    if (s2ok) { e2 = __expf(v2 - mx); sc[tid + 256] = e2; }
    float sum = e1 + e2;
#pragma unroll
    for (int o = 32; o > 0; o >>= 1) sum += __shfl_xor(sum, o, 64);
    if (lane == 0) red[4 + wv] = sum;
    __syncthreads();                                        // (2)
    const float inv = fastrcp(red[4] + red[5] + red[6] + red[7]);

    // ---- combine: 16 LDS rows + 26 REGISTER rows per thread ----
    {
      float a0 = 0, a1 = 0, a2 = 0, a3 = 0, a4 = 0, a5 = 0, a6 = 0, a7 = 0;
      {
        const float* scr = sc + ck * 16;
#pragma unroll
        for (int s5 = 0; s5 < 16; ++s5) {
          const bhalf8 v = *(const bhalf8*)(epL + (size_t)s5 * H_);
          const float wgt = scr[s5];
          a0 += wgt * (float)v[0];
          a1 += wgt * (float)v[1];
          a2 += wgt * (float)v[2];
          a3 += wgt * (float)v[3];
          a4 += wgt * (float)v[4];
          a5 += wgt * (float)v[5];
          a6 += wgt * (float)v[6];
          a7 += wgt * (float)v[7];
        }
      }
      {
        const float* scr = sc + 128 + ck * 26;
#pragma unroll
        for (int s5 = 0; s5 < 26; ++s5) {
          const bhalf8 v = ebr[s5];
          const float wgt = scr[s5];
          a0 += wgt * (float)v[0];
          a1 += wgt * (float)v[1];
          a2 += wgt * (float)v[2];
          a3 += wgt * (float)v[3];
          a4 += wgt * (float)v[4];
          a5 += wgt * (float)v[5];
          a6 += wgt * (float)v[6];
          a7 += wgt * (float)v[7];
        }
      }
      float* pp = pC[ck][cg];
      pp[0] = a0; pp[1] = a1; pp[2] = a2; pp[3] = a3;
      pp[4] = a4; pp[5] = a5; pp[6] = a6; pp[7] = a7;
    }
    __syncthreads();                                        // (3)

    // ---- GRU: cL reduce (inv folded) + h-part BEFORE cL barrier ----
    float r0 = 0, r1 = 0, z0 = 0, z1 = 0, nh0 = 0, nh1 = 0, nx0 = 0, nx1 = 0;
    {
      const int gg = jj >> 3, j = jj & 7;
      float ssum = 0.0f;
#pragma unroll
      for (int c = 0; c < 8; ++c) ssum += pC[c][gg][j];
      cL[jj] = ssum * inv;
    }
#pragma unroll 4
    for (int k8 = 0; k8 < 32; ++k8) {          // h part (reads hc only)
      const bhalf* base = wbT + ((size_t)k8 * 768) * 8;
      const bhalf8 qR = *(const bhalf8*)(base + (size_t)jj * 8);
      const bhalf8 qZ = *(const bhalf8*)(base + (size_t)(256 + jj) * 8);
      const bhalf8 qN = *(const bhalf8*)(base + (size_t)(512 + jj) * 8);
      const float* v = hc + k8 * 8;
      r0 += (float)qR[0]*v[0] + (float)qR[2]*v[2] + (float)qR[4]*v[4] + (float)qR[6]*v[6];
      r1 += (float)qR[1]*v[1] + (float)qR[3]*v[3] + (float)qR[5]*v[5] + (float)qR[7]*v[7];
      z0 += (float)qZ[0]*v[0] + (float)qZ[2]*v[2] + (float)qZ[4]*v[4] + (float)qZ[6]*v[6];
      z1 += (float)qZ[1]*v[1] + (float)qZ[3]*v[3] + (float)qZ[5]*v[5] + (float)qZ[7]*v[7];
      nh0 += (float)qN[0]*v[0] + (float)qN[2]*v[2] + (float)qN[4]*v[4] + (float)qN[6]*v[6];
      nh1 += (float)qN[1]*v[1] + (float)qN[3]*v[3] + (float)qN[5]*v[5] + (float)qN[7]*v[7];
    }
    __syncthreads();                                        // (4) cL ready
#pragma unroll 4
    for (int k8 = 32; k8 < 64; ++k8) {         // c part
      const bhalf* base = wbT + ((size_t)k8 * 768) * 8;
      const bhalf8 qR = *(const bhalf8*)(base + (size_t)jj * 8);
      const bhalf8 qZ = *(const bhalf8*)(base + (size_t)(256 + jj) * 8);
      const bhalf8 qN = *(const bhalf8*)(base + (size_t)(512 + jj) * 8);
      const float* v = cL + (k8 - 32) * 8;
      r0 += (float)qR[0]*v[0] + (float)qR[2]*v[2] + (float)qR[4]*v[4] + (float)qR[6]*v[6];
      r1 += (float)qR[1]*v[1] + (float)qR[3]*v[3] + (float)qR[5]*v[5] + (float)qR[7]*v[7];
      z0 += (float)qZ[0]*v[0] + (float)qZ[2]*v[2] + (float)qZ[4]*v[4] + (float)qZ[6]*v[6];
      z1 += (float)qZ[1]*v[1] + (float)qZ[3]*v[3] + (float)qZ[5]*v[5] + (float)qZ[7]*v[7];
      nx0 += (float)qN[0]*v[0] + (float)qN[2]*v[2] + (float)qN[4]*v[4] + (float)qN[6]*v[6];
      nx1 += (float)qN[1]*v[1] + (float)qN[3]*v[3] + (float)qN[5]*v[5] + (float)qN[7]*v[7];
    }
    {
      const float sR = r0 + r1 + bRv;
      const float sZ = z0 + z1 + bZv;
      const float nh = nh0 + nh1 + bNhv;
      const float nx = nx0 + nx1 + bNxv;
      const float rr = 1.0f / (1.0f + __expf(-sR));
      const float zz = 1.0f / (1.0f + __expf(-sZ));
      const float nn = tanhf(nx + rr * nh);
      hn[jj] = (1.0f - zz) * nn + zz * hc[jj];   // ping-pong: no pre-barrier
    }
    __syncthreads();                                        // (5)

    // ---- out: 256 threads, 16-lane shuffle reduce, y feedback ----
    {
      const float* hv = hn + q_o * 16;
      float a0 = 0, a1 = 0, a2 = 0, a3 = 0;
#pragma unroll
      for (int jv = 0; jv < 4; ++jv) {
        const f32x4 h4 = *(const f32x4*)(hv + jv * 4);
        a0 += ow[jv][0] * h4[0]; a1 += ow[jv][1] * h4[1];
        a2 += ow[jv][2] * h4[2]; a3 += ow[jv][3] * h4[3];
      }
      float a = a0 + a1 + a2 + a3;
      a += __shfl_xor(a, 1, 64); a += __shfl_xor(a, 2, 64);
      a += __shfl_xor(a, 4, 64); a += __shfl_xor(a, 8, 64);
      if (q_o == 0) hn[256 + f_o] = a + outb_f;
    }
    __syncthreads();                                        // (6)
    if (tid < 16) {
      float v = hn[256 + tid] * linw_t;
      v += __shfl_xor(v, 1, 64); v += __shfl_xor(v, 2, 64);
      v += __shfl_xor(v, 4, 64); v += __shfl_xor(v, 8, 64);
      if (tid == 0) dout[(size_t)b * P_ + p] = v + linb0;
    }
  }
}

// ---------------------------------------------------------------------------
extern "C" void kernel_launch(void* const* d_in, const int* in_sizes, int n_in,
                              void* d_out, int out_size, void* d_ws, size_t ws_size,
                              hipStream_t stream)
{
  (void)in_sizes; (void)n_in; (void)out_size;
  const float* xb      = (const float*)d_in[0];
  const float* enc_Wih = (const float*)d_in[1];
  const float* enc_Whh = (const float*)d_in[2];
  const float* enc_bih = (const float*)d_in[3];
  const float* enc_bhh = (const float*)d_in[4];
  const float* att_W   = (const float*)d_in[5];
  const float* att_b   = (const float*)d_in[6];
  const float* dec_Wih = (const float*)d_in[7];
  const float* dec_Whh = (const float*)d_in[8];
  const float* dec_bih = (const float*)d_in[9];
  const float* dec_bhh = (const float*)d_in[10];
  const float* out_W   = (const float*)d_in[11];
  const float* out_b   = (const float*)d_in[12];
  const float* lin_W   = (const float*)d_in[13];
  const float* lin_b   = (const float*)d_in[14];
  float* dout = (float*)d_out;

  char* ws = (char*)d_ws;
  const size_t off_enc = 0;                                     // bf16 enc_out
  const size_t off_hp  = off_enc + (size_t)B_ * S_ * H_ * 2;    // 88,080,384
  const size_t off_hc  = off_hp + (size_t)2 * B_ * H_ * 4;      // hpack u32
  const size_t off_wb  = off_hc + (size_t)B_ * H_ * 4;
  const size_t off_ab  = off_wb + (size_t)64 * 768 * 8 * 2;
  const size_t off_fl  = off_ab + (size_t)36 * 336 * 8 * 2;
  const size_t need    = off_fl + 32 * 8 * sizeof(unsigned int);
  if (ws_size < need) return;

  bhalf* enc_out      = (bhalf*)(ws + off_enc);
  unsigned int* hpack = (unsigned int*)(ws + off_hp);
  float* hcur         = (float*)(ws + off_hc);
  bhalf* wbT          = (bhalf*)(ws + off_wb);
  bhalf* abT          = (bhalf*)(ws + off_ab);
  unsigned int* flags = (unsigned int*)(ws + off_fl);

  (void)hipMemsetAsync(flags, 0, 32 * 8 * sizeof(unsigned int), stream);
  wpack_kernel<<<(64 * 768 * 8 + 255) / 256, 256, 0, stream>>>(dec_Whh, dec_Wih, wbT);
  apack_kernel<<<(36 * 336 * 8 + 255) / 256, 256, 0, stream>>>(att_W, abT);
  enc_kernel<<<256, 128, 0, stream>>>(enc_Whh, enc_Wih, enc_bih, enc_bhh, xb,
                                      enc_out, hcur, hpack, flags);
  dec_kernel<<<B_, 256, 0, stream>>>(wbT, abT, att_b, dec_bih, dec_bhh,
                                     out_W, out_b, lin_W, lin_b,
                                     enc_out, hcur, xb, dout);
}

// Round 15
// 2952.746 us; speedup vs baseline: 1.4693x; 1.4693x over previous
//
#include <hip/hip_runtime.h>
#include <cstdint>
#include <cstddef>

#define B_ 512
#define S_ 336
#define F_ 16
#define H_ 256
#define P_ 48

typedef __bf16 bhalf;
typedef __attribute__((ext_vector_type(8))) __bf16 bhalf8;
typedef __attribute__((ext_vector_type(4))) float f32x4;
typedef __attribute__((ext_vector_type(2))) unsigned long long u64x2;

#define MFMA16(A, Bv, C) __builtin_amdgcn_mfma_f32_16x16x32_bf16((A), (Bv), (C), 0, 0, 0)

__device__ __forceinline__ float fastrcp(float x) { return __builtin_amdgcn_rcpf(x); }
__device__ __forceinline__ float sigm(float x) { return fastrcp(1.0f + __expf(-x)); }
__device__ __forceinline__ float tanh_f(float x) { return 2.0f * fastrcp(1.0f + __expf(-2.0f * x)) - 1.0f; }

__device__ __forceinline__ unsigned short bf_to_u16(bhalf b) {
  return __builtin_bit_cast(unsigned short, b);
}

__device__ __forceinline__ bhalf8 bzero8() {
  bhalf8 v;
#pragma unroll
  for (int j = 0; j < 8; ++j) v[j] = (bhalf)0.0f;
  return v;
}

// ---------------------------------------------------------------------------
// Encoder: weight-stationary MFMA flag pipeline (r8 structure).
// CHANGE vs r13 (ONE mechanism): hi/lo exchange planes stored SEPARATELY in
// consumer-contiguous layout hi2/lo2[slot][B][H/2] (u32 = two adjacent dims).
// Producer: one shfl_xor(.,1) per plane pairs adjacent dims; even lanes store
// the hi word, odd lanes the lo word (same count/bytes/protocol). Consumer:
// 32 u64 loads whose pairs BITCAST straight to bhalf8 fragments — the
// ~150-200 VALU unpack on the load->MFMA critical-path tail is gone.
// ---------------------------------------------------------------------------
__global__ __launch_bounds__(128, 1) void enc_kernel(
    const float* __restrict__ Whh, const float* __restrict__ Wih,
    const float* __restrict__ bih, const float* __restrict__ bhh,
    const float* __restrict__ xb,        // [B][S][F] fp32
    bhalf* __restrict__ enc_out,         // [B][S][H]
    float* __restrict__ hcur,            // [B][H] final h, fp32 exact
    unsigned int* __restrict__ hi2,      // [2][B][H/2] hi-plane pairs
    unsigned int* __restrict__ lo2,      // [2][B][H/2] lo-plane pairs
    unsigned int* __restrict__ flags)    // [32][8] steps-completed counters
{
  const int tid  = threadIdx.x;
  const int lane = tid & 63;
  const int wv   = tid >> 6;
  const int ncol = lane & 15;
  const int quad = lane >> 4;

  const int blk = blockIdx.x;
  const int g   = (blk & 7) * 4 + (blk >> 6);   // group 0..31 (members share XCD)
  const int w   = (blk >> 3) & 7;               // member 0..7
  const int b0  = g * 16;
  const int iw0 = w * 32;
  const int i0  = iw0 + wv * 16;

  bhalf8 bWh[3][9], bWl[3][9];
#pragma unroll
  for (int gg = 0; gg < 3; ++gg) {
    const int jrow = gg * 256 + i0 + ncol;
#pragma unroll
    for (int kt = 0; kt < 9; ++kt) {
      bhalf8 vh = bzero8(), vl = bzero8();
      if (kt < 8) {
        const float* src = Whh + (size_t)jrow * 256 + kt * 32 + quad * 8;
#pragma unroll
        for (int j = 0; j < 8; ++j) {
          const float v = src[j];
          const bhalf h = (bhalf)v;
          vh[j] = h;
          vl[j] = (bhalf)(v - (float)h);
        }
      } else if (quad < 2) {
        const float* src = Wih + (size_t)jrow * 16 + quad * 8;
#pragma unroll
        for (int j = 0; j < 8; ++j) {
          const float v = src[j];
          const bhalf h = (bhalf)v;
          vh[j] = h;
          vl[j] = (bhalf)(v - (float)h);
        }
      }
      bWh[gg][kt] = vh;
      bWl[gg][kt] = vl;
    }
  }

  const int jr = i0 + ncol;
  const float bR  = bih[jr]       + bhh[jr];
  const float bZ  = bih[256 + jr] + bhh[256 + jr];
  const float bNx = bih[512 + jr];
  const float bNh = bhh[512 + jr];

  const int bA = b0 + ncol;

  float hold[4] = {0.0f, 0.0f, 0.0f, 0.0f};

  for (int t = 0; t < S_; ++t) {
    bhalf8 xh = bzero8(), xl = bzero8();
    if (quad < 2) {
      const float* xp = xb + ((size_t)bA * S_ + t) * F_ + quad * 8;
#pragma unroll
      for (int j = 0; j < 8; ++j) {
        const float v = __builtin_nontemporal_load(xp + j);
        const bhalf h = (bhalf)v;
        xh[j] = h;
        xl[j] = (bhalf)(v - (float)h);
      }
    }

    f32x4 aR0 = {0,0,0,0}, aR1 = {0,0,0,0}, aR2 = {0,0,0,0};
    f32x4 aZ0 = {0,0,0,0}, aZ1 = {0,0,0,0}, aZ2 = {0,0,0,0};
    f32x4 aN0 = {0,0,0,0}, aN1 = {0,0,0,0}, aN2 = {0,0,0,0};
    f32x4 aNx = {0,0,0,0};

    // kt = 8: x-part (h-independent -> BEFORE the spin)
    aR0 = MFMA16(xh, bWh[0][8], aR0);
    aR1 = MFMA16(xh, bWl[0][8], aR1);
    aR2 = MFMA16(xl, bWh[0][8], aR2);
    aZ0 = MFMA16(xh, bWh[1][8], aZ0);
    aZ1 = MFMA16(xh, bWl[1][8], aZ1);
    aZ2 = MFMA16(xl, bWh[1][8], aZ2);
    aNx = MFMA16(xh, bWh[2][8], aNx);
    aNx = MFMA16(xh, bWl[2][8], aNx);
    aNx = MFMA16(xl, bWh[2][8], aNx);

    if (t > 0) {
      const unsigned int* fp = &flags[g * 8 + (lane & 7)];
      while (__hip_atomic_load(fp, __ATOMIC_RELAXED, __HIP_MEMORY_SCOPE_AGENT) <
             (unsigned int)t)
        __builtin_amdgcn_s_sleep(1);

      const int slot = (t - 1) & 1;
      const unsigned long long* hi64 =
          (const unsigned long long*)hi2 + ((size_t)slot * B_ + bA) * 64;
      const unsigned long long* lo64 =
          (const unsigned long long*)lo2 + ((size_t)slot * B_ + bA) * 64;

      // all 32 u64 loads issued up front (one L3 latency, r6 pattern)
      unsigned long long wH[16], wL[16];
#pragma unroll
      for (int i = 0; i < 16; ++i)
        wH[i] = __hip_atomic_load(hi64 + (i >> 1) * 8 + quad * 2 + (i & 1),
                                  __ATOMIC_RELAXED, __HIP_MEMORY_SCOPE_AGENT);
#pragma unroll
      for (int i = 0; i < 16; ++i)
        wL[i] = __hip_atomic_load(lo64 + (i >> 1) * 8 + quad * 2 + (i & 1),
                                  __ATOMIC_RELAXED, __HIP_MEMORY_SCOPE_AGENT);

#pragma unroll
      for (int kt = 0; kt < 8; ++kt) {
        const bhalf8 Ah = __builtin_bit_cast(bhalf8, (u64x2){wH[kt * 2], wH[kt * 2 + 1]});
        const bhalf8 Al = __builtin_bit_cast(bhalf8, (u64x2){wL[kt * 2], wL[kt * 2 + 1]});
        aR0 = MFMA16(Ah, bWh[0][kt], aR0);
        aR1 = MFMA16(Ah, bWl[0][kt], aR1);
        aR2 = MFMA16(Al, bWh[0][kt], aR2);
        aZ0 = MFMA16(Ah, bWh[1][kt], aZ0);
        aZ1 = MFMA16(Ah, bWl[1][kt], aZ1);
        aZ2 = MFMA16(Al, bWh[1][kt], aZ2);
        aN0 = MFMA16(Ah, bWh[2][kt], aN0);
        aN1 = MFMA16(Ah, bWl[2][kt], aN1);
        aN2 = MFMA16(Al, bWh[2][kt], aN2);
      }
    }

    // ---- gates (C/D: col = lane&15, row = quad*4 + reg) ----
    const int iL = i0 + ncol;
    bhalf his[4];
#pragma unroll
    for (int r = 0; r < 4; ++r) {
      const float sR  = aR0[r] + aR1[r] + aR2[r] + bR;
      const float sZ  = aZ0[r] + aZ1[r] + aZ2[r] + bZ;
      const float nhv = aN0[r] + aN1[r] + aN2[r] + bNh;
      const float nxv = aNx[r] + bNx;
      const float rr = sigm(sR);
      const float zz = sigm(sZ);
      const float nn = tanh_f(nxv + rr * nhv);
      const float h2 = (1.0f - zz) * nn + zz * hold[r];
      hold[r] = h2;
      his[r] = (bhalf)h2;
      const bhalf lo = (bhalf)(h2 - (float)his[r]);
      // pair adjacent dims via partner lane (ncol^1 holds iL^1)
      const unsigned int myhi = bf_to_u16(his[r]);
      const unsigned int mylo = bf_to_u16(lo);
      const unsigned int othi = (unsigned int)__shfl_xor((int)myhi, 1, 64);
      const unsigned int otlo = (unsigned int)__shfl_xor((int)mylo, 1, 64);
      const int bb = b0 + quad * 4 + r;
      const unsigned int wrd = (ncol & 1) ? (otlo | (mylo << 16))
                                          : (myhi | (othi << 16));
      unsigned int* dst = ((ncol & 1) ? lo2 : hi2) +
                          ((size_t)(t & 1) * B_ + bb) * 128 + (iL >> 1);
      __hip_atomic_store(dst, wrd, __ATOMIC_RELAXED, __HIP_MEMORY_SCOPE_AGENT);
    }

    __syncthreads();   // drains vmcnt(0): exchange stores visible before flag
    if (tid == 0) {
      __hip_atomic_store(&flags[g * 8 + w], (unsigned int)(t + 1),
                         __ATOMIC_RELAXED, __HIP_MEMORY_SCOPE_AGENT);
    }

    // enc_out stores AFTER release (no consumer until dec_kernel).
#pragma unroll
    for (int r = 0; r < 4; ++r) {
      const int bb = b0 + quad * 4 + r;
      __builtin_nontemporal_store(his[r], enc_out + ((size_t)bb * S_ + t) * H_ + iL);
    }
  }

#pragma unroll
  for (int r = 0; r < 4; ++r)
    hcur[(size_t)(b0 + quad * 4 + r) * H_ + i0 + ncol] = hold[r];
}

// ---------------------------------------------------------------------------
// Prep: dec GRU weights -> TRANSPOSED bf16 pack wbT[64][768][8]
// ---------------------------------------------------------------------------
__global__ __launch_bounds__(256) void wpack_kernel(const float* __restrict__ Whh,
                                                    const float* __restrict__ Wih,
                                                    bhalf* __restrict__ wbT) {
  const int idx = blockIdx.x * 256 + threadIdx.x;
  if (idx >= 64 * 768 * 8) return;
  const int j = idx & 7;
  const int row = (idx >> 3) % 768;
  const int k8 = idx / (768 * 8);
  const int k = k8 * 8 + j;
  const float v = (k < 256) ? Whh[(size_t)row * 256 + k]
                            : Wih[(size_t)row * 256 + (k - 256)];
  wbT[idx] = (bhalf)v;
}

// ---------------------------------------------------------------------------
// Prep: attW -> bf16 TRANSPOSED pack abT[36][336][8] (zero-padded k>=272)
// ---------------------------------------------------------------------------
__global__ __launch_bounds__(256) void apack_kernel(const float* __restrict__ attW,
                                                    bhalf* __restrict__ abT) {
  const int idx = blockIdx.x * 256 + threadIdx.x;
  if (idx >= 36 * 336 * 8) return;
  const int j = idx & 7;
  const int s = (idx >> 3) % 336;
  const int k8 = idx / (8 * 336);
  const int k = k8 * 8 + j;
  abT[idx] = (k < 272) ? (bhalf)attW[(size_t)s * 272 + k] : (bhalf)0.0f;
}

// ---------------------------------------------------------------------------
// Decoder v7 (r13 verified BEST; EXACT revert — r14's 26-row register hoist
// refuted: persistent 104-VGPR array starved the wbT load pipeline, dec
// 1370->2887 despite FETCH 1.45GB->47MB. dec is TLP-bound, not traffic-bound).
// Uniform combine split: encL caches 128 rows; every thread does 16 LDS rows
// + 26 global rows.
// ---------------------------------------------------------------------------
__global__ __launch_bounds__(256) void dec_kernel(
    const bhalf* __restrict__ wbT,      // [64][768][8]
    const bhalf* __restrict__ abT,      // [36][336][8]
    const float* __restrict__ attb,
    const float* __restrict__ bih, const float* __restrict__ bhh,
    const float* __restrict__ outW, const float* __restrict__ outb,
    const float* __restrict__ linW, const float* __restrict__ linb,
    const bhalf* __restrict__ enc_out, const float* __restrict__ hcur,
    const float* __restrict__ xb, float* __restrict__ dout)
{
  __shared__ __align__(16) bhalf encL[128 * 256];   // 65536 B: s<128 cache
  __shared__ __align__(16) float hybuf[2][288];     // ping-pong [h|y|pad]
  __shared__ __align__(16) float cL[256];
  __shared__ float sc[S_];
  __shared__ float pC[8][32][9];    // combine partials, padded (bank-safe)
  __shared__ float red[8];
  const int tid  = threadIdx.x;
  const int lane = tid & 63;
  const int wv   = tid >> 6;
  const int b    = blockIdx.x;
  const int jj   = tid;
  const int cg   = tid & 31;        // combine col-group (8 cols)
  const int ck   = tid >> 5;        // combine chunk: 16 LDS + 26 global rows
  const int s2ok = tid < 80;        // handles second score row s=tid+256
  const int f_o  = tid >> 4;        // out-phase f
  const int q_o  = tid & 15;        // out-phase k-chunk

  // one-time: cache enc_out rows [0,128) (coalesced 16B)
  {
    const bhalf8* src = (const bhalf8*)(enc_out + (size_t)b * S_ * H_);
    bhalf8* dst = (bhalf8*)encL;
    for (int it = tid; it < 128 * 32; it += 256) dst[it] = src[it];
  }

  hybuf[0][tid] = hcur[(size_t)b * H_ + tid];
  if (tid < 16) {
    hybuf[0][256 + tid] = xb[((size_t)b * S_ + (S_ - 1)) * F_ + tid];
    hybuf[1][256 + tid] = 0.0f;
  } else if (tid < 32) {
    hybuf[0][256 + tid] = 0.0f;
    hybuf[1][256 + tid] = 0.0f;
  }

  const float bRv  = bih[jj]       + bhh[jj];
  const float bZv  = bih[256 + jj] + bhh[256 + jj];
  const float bNxv = bih[512 + jj];
  const float bNhv = bhh[512 + jj];

  const float ab1 = attb[tid];
  const float ab2 = s2ok ? attb[tid + 256] : 0.0f;

  f32x4 ow[4];
  {
    const float* wrp = outW + (size_t)f_o * H_ + q_o * 16;
#pragma unroll
    for (int jv = 0; jv < 4; ++jv) ow[jv] = *(const f32x4*)(wrp + jv * 4);
  }
  const float outb_f = outb[f_o];
  const float linw_t = (tid < 16) ? linW[tid] : 0.0f;
  const float linb0  = linb[0];

  const bhalf* epL = encL + (size_t)(ck * 16) * H_ + cg * 8;                    // 16 LDS rows
  const bhalf* epC = enc_out + ((size_t)b * S_ + 128 + ck * 26) * H_ + cg * 8;  // 26 global rows
  __syncthreads();

  for (int p = 0; p < P_; ++p) {
    float* hc = hybuf[p & 1];          // current h|y (read)
    float* hn = hybuf[(p & 1) ^ 1];    // next h|y (write)

    // ---- scores: registers only ----
    float v1, v2 = -3.0e38f;
    {
      float d0 = 0, d1 = 0, d2 = 0, d3 = 0;
#pragma unroll 4
      for (int k8 = 0; k8 < 36; ++k8) {
        const bhalf8 q = *(const bhalf8*)(abT + ((size_t)k8 * S_ + tid) * 8);
        const float* v = hc + k8 * 8;
        d0 += (float)q[0] * v[0] + (float)q[4] * v[4];
        d1 += (float)q[1] * v[1] + (float)q[5] * v[5];
        d2 += (float)q[2] * v[2] + (float)q[6] * v[6];
        d3 += (float)q[3] * v[3] + (float)q[7] * v[7];
      }
      v1 = d0 + d1 + d2 + d3 + ab1;
    }
    if (s2ok) {
      float d0 = 0, d1 = 0, d2 = 0, d3 = 0;
#pragma unroll 4
      for (int k8 = 0; k8 < 36; ++k8) {
        const bhalf8 q = *(const bhalf8*)(abT + ((size_t)k8 * S_ + tid + 256) * 8);
        const float* v = hc + k8 * 8;
        d0 += (float)q[0] * v[0] + (float)q[4] * v[4];
        d1 += (float)q[1] * v[1] + (float)q[5] * v[5];
        d2 += (float)q[2] * v[2] + (float)q[6] * v[6];
        d3 += (float)q[3] * v[3] + (float)q[7] * v[7];
      }
      v2 = d0 + d1 + d2 + d3 + ab2;
    }

    // ---- softmax: max/sum reduces; exp stored UNNORMALIZED ----
    float m = fmaxf(v1, v2);
#pragma unroll
    for (int o = 32; o > 0; o >>= 1) m = fmaxf(m, __shfl_xor(m, o, 64));
    if (lane == 0) red[wv] = m;
    __syncthreads();                                        // (1)
    const float mx = fmaxf(fmaxf(red[0], red[1]), fmaxf(red[2], red[3]));
    const float e1 = __expf(v1 - mx);
    sc[tid] = e1;
    float e2 = 0.0f;
    if (s2ok) { e2 = __expf(v2 - mx); sc[tid + 256] = e2; }
    float sum = e1 + e2;
#pragma unroll
    for (int o = 32; o > 0; o >>= 1) sum += __shfl_xor(sum, o, 64);
    if (lane == 0) red[4 + wv] = sum;
    __syncthreads();                                        // (2)
    const float inv = fastrcp(red[4] + red[5] + red[6] + red[7]);

    // ---- combine: UNIFORM per thread = 16 LDS rows + 26 global rows ----
    {
      float a0 = 0, a1 = 0, a2 = 0, a3 = 0, a4 = 0, a5 = 0, a6 = 0, a7 = 0;
      {
        const float* scr = sc + ck * 16;
#pragma unroll
        for (int s5 = 0; s5 < 16; ++s5) {
          const bhalf8 v = *(const bhalf8*)(epL + (size_t)s5 * H_);
          const float wgt = scr[s5];
          a0 += wgt * (float)v[0];
          a1 += wgt * (float)v[1];
          a2 += wgt * (float)v[2];
          a3 += wgt * (float)v[3];
          a4 += wgt * (float)v[4];
          a5 += wgt * (float)v[5];
          a6 += wgt * (float)v[6];
          a7 += wgt * (float)v[7];
        }
      }
      {
        const float* scr = sc + 128 + ck * 26;
#pragma unroll 6
        for (int s5 = 0; s5 < 26; ++s5) {
          const bhalf8 v = *(const bhalf8*)(epC + (size_t)s5 * H_);
          const float wgt = scr[s5];
          a0 += wgt * (float)v[0];
          a1 += wgt * (float)v[1];
          a2 += wgt * (float)v[2];
          a3 += wgt * (float)v[3];
          a4 += wgt * (float)v[4];
          a5 += wgt * (float)v[5];
          a6 += wgt * (float)v[6];
          a7 += wgt * (float)v[7];
        }
      }
      float* pp = pC[ck][cg];
      pp[0] = a0; pp[1] = a1; pp[2] = a2; pp[3] = a3;
      pp[4] = a4; pp[5] = a5; pp[6] = a6; pp[7] = a7;
    }
    __syncthreads();                                        // (3)

    // ---- GRU: cL reduce (inv folded) + h-part BEFORE cL barrier ----
    float r0 = 0, r1 = 0, z0 = 0, z1 = 0, nh0 = 0, nh1 = 0, nx0 = 0, nx1 = 0;
    {
      const int gg = jj >> 3, j = jj & 7;
      float ssum = 0.0f;
#pragma unroll
      for (int c = 0; c < 8; ++c) ssum += pC[c][gg][j];
      cL[jj] = ssum * inv;
    }
#pragma unroll 4
    for (int k8 = 0; k8 < 32; ++k8) {          // h part (reads hc only)
      const bhalf* base = wbT + ((size_t)k8 * 768) * 8;
      const bhalf8 qR = *(const bhalf8*)(base + (size_t)jj * 8);
      const bhalf8 qZ = *(const bhalf8*)(base + (size_t)(256 + jj) * 8);
      const bhalf8 qN = *(const bhalf8*)(base + (size_t)(512 + jj) * 8);
      const float* v = hc + k8 * 8;
      r0 += (float)qR[0]*v[0] + (float)qR[2]*v[2] + (float)qR[4]*v[4] + (float)qR[6]*v[6];
      r1 += (float)qR[1]*v[1] + (float)qR[3]*v[3] + (float)qR[5]*v[5] + (float)qR[7]*v[7];
      z0 += (float)qZ[0]*v[0] + (float)qZ[2]*v[2] + (float)qZ[4]*v[4] + (float)qZ[6]*v[6];
      z1 += (float)qZ[1]*v[1] + (float)qZ[3]*v[3] + (float)qZ[5]*v[5] + (float)qZ[7]*v[7];
      nh0 += (float)qN[0]*v[0] + (float)qN[2]*v[2] + (float)qN[4]*v[4] + (float)qN[6]*v[6];
      nh1 += (float)qN[1]*v[1] + (float)qN[3]*v[3] + (float)qN[5]*v[5] + (float)qN[7]*v[7];
    }
    __syncthreads();                                        // (4) cL ready
#pragma unroll 4
    for (int k8 = 32; k8 < 64; ++k8) {         // c part
      const bhalf* base = wbT + ((size_t)k8 * 768) * 8;
      const bhalf8 qR = *(const bhalf8*)(base + (size_t)jj * 8);
      const bhalf8 qZ = *(const bhalf8*)(base + (size_t)(256 + jj) * 8);
      const bhalf8 qN = *(const bhalf8*)(base + (size_t)(512 + jj) * 8);
      const float* v = cL + (k8 - 32) * 8;
      r0 += (float)qR[0]*v[0] + (float)qR[2]*v[2] + (float)qR[4]*v[4] + (float)qR[6]*v[6];
      r1 += (float)qR[1]*v[1] + (float)qR[3]*v[3] + (float)qR[5]*v[5] + (float)qR[7]*v[7];
      z0 += (float)qZ[0]*v[0] + (float)qZ[2]*v[2] + (float)qZ[4]*v[4] + (float)qZ[6]*v[6];
      z1 += (float)qZ[1]*v[1] + (float)qZ[3]*v[3] + (float)qZ[5]*v[5] + (float)qZ[7]*v[7];
      nx0 += (float)qN[0]*v[0] + (float)qN[2]*v[2] + (float)qN[4]*v[4] + (float)qN[6]*v[6];
      nx1 += (float)qN[1]*v[1] + (float)qN[3]*v[3] + (float)qN[5]*v[5] + (float)qN[7]*v[7];
    }
    {
      const float sR = r0 + r1 + bRv;
      const float sZ = z0 + z1 + bZv;
      const float nh = nh0 + nh1 + bNhv;
      const float nx = nx0 + nx1 + bNxv;
      const float rr = 1.0f / (1.0f + __expf(-sR));
      const float zz = 1.0f / (1.0f + __expf(-sZ));
      const float nn = tanhf(nx + rr * nh);
      hn[jj] = (1.0f - zz) * nn + zz * hc[jj];   // ping-pong: no pre-barrier
    }
    __syncthreads();                                        // (5)

    // ---- out: 256 threads, 16-lane shuffle reduce, y feedback ----
    {
      const float* hv = hn + q_o * 16;
      float a0 = 0, a1 = 0, a2 = 0, a3 = 0;
#pragma unroll
      for (int jv = 0; jv < 4; ++jv) {
        const f32x4 h4 = *(const f32x4*)(hv + jv * 4);
        a0 += ow[jv][0] * h4[0]; a1 += ow[jv][1] * h4[1];
        a2 += ow[jv][2] * h4[2]; a3 += ow[jv][3] * h4[3];
      }
      float a = a0 + a1 + a2 + a3;
      a += __shfl_xor(a, 1, 64); a += __shfl_xor(a, 2, 64);
      a += __shfl_xor(a, 4, 64); a += __shfl_xor(a, 8, 64);
      if (q_o == 0) hn[256 + f_o] = a + outb_f;
    }
    __syncthreads();                                        // (6)
    if (tid < 16) {
      float v = hn[256 + tid] * linw_t;
      v += __shfl_xor(v, 1, 64); v += __shfl_xor(v, 2, 64);
      v += __shfl_xor(v, 4, 64); v += __shfl_xor(v, 8, 64);
      if (tid == 0) dout[(size_t)b * P_ + p] = v + linb0;
    }
  }
}

// ---------------------------------------------------------------------------
extern "C" void kernel_launch(void* const* d_in, const int* in_sizes, int n_in,
                              void* d_out, int out_size, void* d_ws, size_t ws_size,
                              hipStream_t stream)
{
  (void)in_sizes; (void)n_in; (void)out_size;
  const float* xb      = (const float*)d_in[0];
  const float* enc_Wih = (const float*)d_in[1];
  const float* enc_Whh = (const float*)d_in[2];
  const float* enc_bih = (const float*)d_in[3];
  const float* enc_bhh = (const float*)d_in[4];
  const float* att_W   = (const float*)d_in[5];
  const float* att_b   = (const float*)d_in[6];
  const float* dec_Wih = (const float*)d_in[7];
  const float* dec_Whh = (const float*)d_in[8];
  const float* dec_bih = (const float*)d_in[9];
  const float* dec_bhh = (const float*)d_in[10];
  const float* out_W   = (const float*)d_in[11];
  const float* out_b   = (const float*)d_in[12];
  const float* lin_W   = (const float*)d_in[13];
  const float* lin_b   = (const float*)d_in[14];
  float* dout = (float*)d_out;

  char* ws = (char*)d_ws;
  const size_t off_enc = 0;                                     // bf16 enc_out
  const size_t off_hi  = off_enc + (size_t)B_ * S_ * H_ * 2;    // 88,080,384
  const size_t off_lo  = off_hi + (size_t)2 * B_ * (H_ / 2) * 4;
  const size_t off_hc  = off_lo + (size_t)2 * B_ * (H_ / 2) * 4;
  const size_t off_wb  = off_hc + (size_t)B_ * H_ * 4;
  const size_t off_ab  = off_wb + (size_t)64 * 768 * 8 * 2;
  const size_t off_fl  = off_ab + (size_t)36 * 336 * 8 * 2;
  const size_t need    = off_fl + 32 * 8 * sizeof(unsigned int);
  if (ws_size < need) return;

  bhalf* enc_out      = (bhalf*)(ws + off_enc);
  unsigned int* hi2   = (unsigned int*)(ws + off_hi);
  unsigned int* lo2   = (unsigned int*)(ws + off_lo);
  float* hcur         = (float*)(ws + off_hc);
  bhalf* wbT          = (bhalf*)(ws + off_wb);
  bhalf* abT          = (bhalf*)(ws + off_ab);
  unsigned int* flags = (unsigned int*)(ws + off_fl);

  (void)hipMemsetAsync(flags, 0, 32 * 8 * sizeof(unsigned int), stream);
  wpack_kernel<<<(64 * 768 * 8 + 255) / 256, 256, 0, stream>>>(dec_Whh, dec_Wih, wbT);
  apack_kernel<<<(36 * 336 * 8 + 255) / 256, 256, 0, stream>>>(att_W, abT);
  enc_kernel<<<256, 128, 0, stream>>>(enc_Whh, enc_Wih, enc_bih, enc_bhh, xb,
                                      enc_out, hcur, hi2, lo2, flags);
  dec_kernel<<<B_, 256, 0, stream>>>(wbT, abT, att_b, dec_bih, dec_bhh,
                                     out_W, out_b, lin_W, lin_b,
                                     enc_out, hcur, xb, dout);
}

// Round 16
// 2901.265 us; speedup vs baseline: 1.4954x; 1.0177x over previous
//
#include <hip/hip_runtime.h>
#include <cstdint>
#include <cstddef>

#define B_ 512
#define S_ 336
#define F_ 16
#define H_ 256
#define P_ 48

typedef __bf16 bhalf;
typedef __attribute__((ext_vector_type(8))) __bf16 bhalf8;
typedef __attribute__((ext_vector_type(4))) float f32x4;

#define MFMA16(A, Bv, C) __builtin_amdgcn_mfma_f32_16x16x32_bf16((A), (Bv), (C), 0, 0, 0)

__device__ __forceinline__ float fastrcp(float x) { return __builtin_amdgcn_rcpf(x); }
__device__ __forceinline__ float sigm(float x) { return fastrcp(1.0f + __expf(-x)); }
__device__ __forceinline__ float tanh_f(float x) { return 2.0f * fastrcp(1.0f + __expf(-2.0f * x)) - 1.0f; }

__device__ __forceinline__ bhalf u16_to_bf(unsigned int u) {
  return __builtin_bit_cast(__bf16, (unsigned short)u);
}
__device__ __forceinline__ unsigned short bf_to_u16(bhalf b) {
  return __builtin_bit_cast(unsigned short, b);
}

__device__ __forceinline__ bhalf8 bzero8() {
  bhalf8 v;
#pragma unroll
  for (int j = 0; j < 8; ++j) v[j] = (bhalf)0.0f;
  return v;
}

// ---------------------------------------------------------------------------
// FINAL (r13 config, session best 2915us from 4272us baseline).
// Encoder: weight-stationary MFMA flag pipeline. Structure floor ~1525us:
// agent-scope L3 h-exchange x 336 sequential steps. Verified refutations:
// fan-in 4 (r9), 2 blocks/CU (r5), one-block-owns-h (r11), nt hints (r4),
// split hi/lo planes (r15 null). Wins kept: per-member store flags + lane
// spin (r3), batched 32-load wbuf consume (r6).
// ---------------------------------------------------------------------------
__global__ __launch_bounds__(128, 1) void enc_kernel(
    const float* __restrict__ Whh, const float* __restrict__ Wih,
    const float* __restrict__ bih, const float* __restrict__ bhh,
    const float* __restrict__ xb,        // [B][S][F] fp32
    bhalf* __restrict__ enc_out,         // [B][S][H]
    float* __restrict__ hcur,            // [B][H] final h, fp32 exact
    unsigned int* __restrict__ hpack,    // [2][B][H] relaxed-atomic channel
    unsigned int* __restrict__ flags)    // [32][8] steps-completed counters
{
  const int tid  = threadIdx.x;
  const int lane = tid & 63;
  const int wv   = tid >> 6;
  const int ncol = lane & 15;
  const int quad = lane >> 4;

  const int blk = blockIdx.x;
  const int g   = (blk & 7) * 4 + (blk >> 6);   // group 0..31 (members share XCD)
  const int w   = (blk >> 3) & 7;               // member 0..7
  const int b0  = g * 16;
  const int iw0 = w * 32;
  const int i0  = iw0 + wv * 16;

  bhalf8 bWh[3][9], bWl[3][9];
#pragma unroll
  for (int gg = 0; gg < 3; ++gg) {
    const int jrow = gg * 256 + i0 + ncol;
#pragma unroll
    for (int kt = 0; kt < 9; ++kt) {
      bhalf8 vh = bzero8(), vl = bzero8();
      if (kt < 8) {
        const float* src = Whh + (size_t)jrow * 256 + kt * 32 + quad * 8;
#pragma unroll
        for (int j = 0; j < 8; ++j) {
          const float v = src[j];
          const bhalf h = (bhalf)v;
          vh[j] = h;
          vl[j] = (bhalf)(v - (float)h);
        }
      } else if (quad < 2) {
        const float* src = Wih + (size_t)jrow * 16 + quad * 8;
#pragma unroll
        for (int j = 0; j < 8; ++j) {
          const float v = src[j];
          const bhalf h = (bhalf)v;
          vh[j] = h;
          vl[j] = (bhalf)(v - (float)h);
        }
      }
      bWh[gg][kt] = vh;
      bWl[gg][kt] = vl;
    }
  }

  const int jr = i0 + ncol;
  const float bR  = bih[jr]       + bhh[jr];
  const float bZ  = bih[256 + jr] + bhh[256 + jr];
  const float bNx = bih[512 + jr];
  const float bNh = bhh[512 + jr];

  const int bA = b0 + ncol;
  const int kA = quad * 8;

  float hold[4] = {0.0f, 0.0f, 0.0f, 0.0f};

  for (int t = 0; t < S_; ++t) {
    bhalf8 xh = bzero8(), xl = bzero8();
    if (quad < 2) {
      const float* xp = xb + ((size_t)bA * S_ + t) * F_ + quad * 8;
#pragma unroll
      for (int j = 0; j < 8; ++j) {
        const float v = __builtin_nontemporal_load(xp + j);
        const bhalf h = (bhalf)v;
        xh[j] = h;
        xl[j] = (bhalf)(v - (float)h);
      }
    }

    f32x4 aR0 = {0,0,0,0}, aR1 = {0,0,0,0}, aR2 = {0,0,0,0};
    f32x4 aZ0 = {0,0,0,0}, aZ1 = {0,0,0,0}, aZ2 = {0,0,0,0};
    f32x4 aN0 = {0,0,0,0}, aN1 = {0,0,0,0}, aN2 = {0,0,0,0};
    f32x4 aNx = {0,0,0,0};

    // kt = 8: x-part (h-independent -> BEFORE the spin)
    aR0 = MFMA16(xh, bWh[0][8], aR0);
    aR1 = MFMA16(xh, bWl[0][8], aR1);
    aR2 = MFMA16(xl, bWh[0][8], aR2);
    aZ0 = MFMA16(xh, bWh[1][8], aZ0);
    aZ1 = MFMA16(xh, bWl[1][8], aZ1);
    aZ2 = MFMA16(xl, bWh[1][8], aZ2);
    aNx = MFMA16(xh, bWh[2][8], aNx);
    aNx = MFMA16(xh, bWl[2][8], aNx);
    aNx = MFMA16(xl, bWh[2][8], aNx);

    if (t > 0) {
      const unsigned int* fp = &flags[g * 8 + (lane & 7)];
      while (__hip_atomic_load(fp, __ATOMIC_RELAXED, __HIP_MEMORY_SCOPE_AGENT) <
             (unsigned int)t)
        __builtin_amdgcn_s_sleep(1);

      const int slot = (t - 1) & 1;
      const unsigned long long* hp64 =
          (const unsigned long long*)(hpack + ((size_t)slot * B_ + bA) * H_ + kA);

      unsigned long long wbuf[32];
#pragma unroll
      for (int i = 0; i < 32; ++i)
        wbuf[i] = __hip_atomic_load(hp64 + (i >> 2) * 16 + (i & 3),
                                    __ATOMIC_RELAXED, __HIP_MEMORY_SCOPE_AGENT);

#pragma unroll
      for (int kt = 0; kt < 8; ++kt) {
        bhalf8 Ah, Al;
#pragma unroll
        for (int j2 = 0; j2 < 4; ++j2) {
          const unsigned long long w2 = wbuf[kt * 4 + j2];
          Ah[2 * j2]     = u16_to_bf((unsigned int)w2);
          Al[2 * j2]     = u16_to_bf((unsigned int)(w2 >> 16));
          Ah[2 * j2 + 1] = u16_to_bf((unsigned int)(w2 >> 32));
          Al[2 * j2 + 1] = u16_to_bf((unsigned int)(w2 >> 48));
        }
        aR0 = MFMA16(Ah, bWh[0][kt], aR0);
        aR1 = MFMA16(Ah, bWl[0][kt], aR1);
        aR2 = MFMA16(Al, bWh[0][kt], aR2);
        aZ0 = MFMA16(Ah, bWh[1][kt], aZ0);
        aZ1 = MFMA16(Ah, bWl[1][kt], aZ1);
        aZ2 = MFMA16(Al, bWh[1][kt], aZ2);
        aN0 = MFMA16(Ah, bWh[2][kt], aN0);
        aN1 = MFMA16(Ah, bWl[2][kt], aN1);
        aN2 = MFMA16(Al, bWh[2][kt], aN2);
      }
    }

    const int iL = i0 + ncol;
    bhalf his[4];
#pragma unroll
    for (int r = 0; r < 4; ++r) {
      const float sR  = aR0[r] + aR1[r] + aR2[r] + bR;
      const float sZ  = aZ0[r] + aZ1[r] + aZ2[r] + bZ;
      const float nhv = aN0[r] + aN1[r] + aN2[r] + bNh;
      const float nxv = aNx[r] + bNx;
      const float rr = sigm(sR);
      const float zz = sigm(sZ);
      const float nn = tanh_f(nxv + rr * nhv);
      const float h2 = (1.0f - zz) * nn + zz * hold[r];
      hold[r] = h2;
      his[r] = (bhalf)h2;
      const bhalf lo = (bhalf)(h2 - (float)his[r]);
      const int bb = b0 + quad * 4 + r;
      const unsigned int wrd =
          (unsigned int)bf_to_u16(his[r]) | ((unsigned int)bf_to_u16(lo) << 16);
      __hip_atomic_store(&hpack[((size_t)(t & 1) * B_ + bb) * H_ + iL], wrd,
                         __ATOMIC_RELAXED, __HIP_MEMORY_SCOPE_AGENT);
    }

    __syncthreads();
    if (tid == 0) {
      __hip_atomic_store(&flags[g * 8 + w], (unsigned int)(t + 1),
                         __ATOMIC_RELAXED, __HIP_MEMORY_SCOPE_AGENT);
    }

#pragma unroll
    for (int r = 0; r < 4; ++r) {
      const int bb = b0 + quad * 4 + r;
      __builtin_nontemporal_store(his[r], enc_out + ((size_t)bb * S_ + t) * H_ + iL);
    }
  }

#pragma unroll
  for (int r = 0; r < 4; ++r)
    hcur[(size_t)(b0 + quad * 4 + r) * H_ + i0 + ncol] = hold[r];
}

// ---------------------------------------------------------------------------
// Prep: dec GRU weights -> TRANSPOSED bf16 pack wbT[64][768][8]
// ---------------------------------------------------------------------------
__global__ __launch_bounds__(256) void wpack_kernel(const float* __restrict__ Whh,
                                                    const float* __restrict__ Wih,
                                                    bhalf* __restrict__ wbT) {
  const int idx = blockIdx.x * 256 + threadIdx.x;
  if (idx >= 64 * 768 * 8) return;
  const int j = idx & 7;
  const int row = (idx >> 3) % 768;
  const int k8 = idx / (768 * 8);
  const int k = k8 * 8 + j;
  const float v = (k < 256) ? Whh[(size_t)row * 256 + k]
                            : Wih[(size_t)row * 256 + (k - 256)];
  wbT[idx] = (bhalf)v;
}

// ---------------------------------------------------------------------------
// Prep: attW -> bf16 TRANSPOSED pack abT[36][336][8] (zero-padded k>=272)
// ---------------------------------------------------------------------------
__global__ __launch_bounds__(256) void apack_kernel(const float* __restrict__ attW,
                                                    bhalf* __restrict__ abT) {
  const int idx = blockIdx.x * 256 + threadIdx.x;
  if (idx >= 36 * 336 * 8) return;
  const int j = idx & 7;
  const int s = (idx >> 3) % 336;
  const int k8 = idx / (8 * 336);
  const int k = k8 * 8 + j;
  abT[idx] = (k < 272) ? (bhalf)attW[(size_t)s * 272 + k] : (bhalf)0.0f;
}

// ---------------------------------------------------------------------------
// Decoder v7 (r13 verified BEST). TLP-bound at 2 blocks/CU (grid-capped).
// Verified refutations: 26-row reg hoist (r14), 2-row/block (r10), f32
// weights (r12), deep reg pipelines (r1/r7). Wins kept: encL 128-row LDS
// cache + UNIFORM combine split (16 LDS + 26 global rows/thread), 6
// barriers/step, reg-resident scores, inv folded into cL reduce, hybuf
// ping-pong, shuffle-reduced out/lin.
// ---------------------------------------------------------------------------
__global__ __launch_bounds__(256) void dec_kernel(
    const bhalf* __restrict__ wbT,      // [64][768][8]
    const bhalf* __restrict__ abT,      // [36][336][8]
    const float* __restrict__ attb,
    const float* __restrict__ bih, const float* __restrict__ bhh,
    const float* __restrict__ outW, const float* __restrict__ outb,
    const float* __restrict__ linW, const float* __restrict__ linb,
    const bhalf* __restrict__ enc_out, const float* __restrict__ hcur,
    const float* __restrict__ xb, float* __restrict__ dout)
{
  __shared__ __align__(16) bhalf encL[128 * 256];   // 65536 B: s<128 cache
  __shared__ __align__(16) float hybuf[2][288];     // ping-pong [h|y|pad]
  __shared__ __align__(16) float cL[256];
  __shared__ float sc[S_];
  __shared__ float pC[8][32][9];    // combine partials, padded (bank-safe)
  __shared__ float red[8];
  const int tid  = threadIdx.x;
  const int lane = tid & 63;
  const int wv   = tid >> 6;
  const int b    = blockIdx.x;
  const int jj   = tid;
  const int cg   = tid & 31;        // combine col-group (8 cols)
  const int ck   = tid >> 5;        // combine chunk: 16 LDS + 26 global rows
  const int s2ok = tid < 80;        // handles second score row s=tid+256
  const int f_o  = tid >> 4;        // out-phase f
  const int q_o  = tid & 15;        // out-phase k-chunk

  // one-time: cache enc_out rows [0,128) (coalesced 16B)
  {
    const bhalf8* src = (const bhalf8*)(enc_out + (size_t)b * S_ * H_);
    bhalf8* dst = (bhalf8*)encL;
    for (int it = tid; it < 128 * 32; it += 256) dst[it] = src[it];
  }

  hybuf[0][tid] = hcur[(size_t)b * H_ + tid];
  if (tid < 16) {
    hybuf[0][256 + tid] = xb[((size_t)b * S_ + (S_ - 1)) * F_ + tid];
    hybuf[1][256 + tid] = 0.0f;
  } else if (tid < 32) {
    hybuf[0][256 + tid] = 0.0f;
    hybuf[1][256 + tid] = 0.0f;
  }

  const float bRv  = bih[jj]       + bhh[jj];
  const float bZv  = bih[256 + jj] + bhh[256 + jj];
  const float bNxv = bih[512 + jj];
  const float bNhv = bhh[512 + jj];

  const float ab1 = attb[tid];
  const float ab2 = s2ok ? attb[tid + 256] : 0.0f;

  f32x4 ow[4];
  {
    const float* wrp = outW + (size_t)f_o * H_ + q_o * 16;
#pragma unroll
    for (int jv = 0; jv < 4; ++jv) ow[jv] = *(const f32x4*)(wrp + jv * 4);
  }
  const float outb_f = outb[f_o];
  const float linw_t = (tid < 16) ? linW[tid] : 0.0f;
  const float linb0  = linb[0];

  const bhalf* epL = encL + (size_t)(ck * 16) * H_ + cg * 8;                    // 16 LDS rows
  const bhalf* epC = enc_out + ((size_t)b * S_ + 128 + ck * 26) * H_ + cg * 8;  // 26 global rows
  __syncthreads();

  for (int p = 0; p < P_; ++p) {
    float* hc = hybuf[p & 1];          // current h|y (read)
    float* hn = hybuf[(p & 1) ^ 1];    // next h|y (write)

    // ---- scores: registers only ----
    float v1, v2 = -3.0e38f;
    {
      float d0 = 0, d1 = 0, d2 = 0, d3 = 0;
#pragma unroll 4
      for (int k8 = 0; k8 < 36; ++k8) {
        const bhalf8 q = *(const bhalf8*)(abT + ((size_t)k8 * S_ + tid) * 8);
        const float* v = hc + k8 * 8;
        d0 += (float)q[0] * v[0] + (float)q[4] * v[4];
        d1 += (float)q[1] * v[1] + (float)q[5] * v[5];
        d2 += (float)q[2] * v[2] + (float)q[6] * v[6];
        d3 += (float)q[3] * v[3] + (float)q[7] * v[7];
      }
      v1 = d0 + d1 + d2 + d3 + ab1;
    }
    if (s2ok) {
      float d0 = 0, d1 = 0, d2 = 0, d3 = 0;
#pragma unroll 4
      for (int k8 = 0; k8 < 36; ++k8) {
        const bhalf8 q = *(const bhalf8*)(abT + ((size_t)k8 * S_ + tid + 256) * 8);
        const float* v = hc + k8 * 8;
        d0 += (float)q[0] * v[0] + (float)q[4] * v[4];
        d1 += (float)q[1] * v[1] + (float)q[5] * v[5];
        d2 += (float)q[2] * v[2] + (float)q[6] * v[6];
        d3 += (float)q[3] * v[3] + (float)q[7] * v[7];
      }
      v2 = d0 + d1 + d2 + d3 + ab2;
    }

    // ---- softmax: max/sum reduces; exp stored UNNORMALIZED ----
    float m = fmaxf(v1, v2);
#pragma unroll
    for (int o = 32; o > 0; o >>= 1) m = fmaxf(m, __shfl_xor(m, o, 64));
    if (lane == 0) red[wv] = m;
    __syncthreads();                                        // (1)
    const float mx = fmaxf(fmaxf(red[0], red[1]), fmaxf(red[2], red[3]));
    const float e1 = __expf(v1 - mx);
    sc[tid] = e1;
    float e2 = 0.0f;
    if (s2ok) { e2 = __expf(v2 - mx); sc[tid + 256] = e2; }
    float sum = e1 + e2;
#pragma unroll
    for (int o = 32; o > 0; o >>= 1) sum += __shfl_xor(sum, o, 64);
    if (lane == 0) red[4 + wv] = sum;
    __syncthreads();                                        // (2)
    const float inv = fastrcp(red[4] + red[5] + red[6] + red[7]);

    // ---- combine: UNIFORM per thread = 16 LDS rows + 26 global rows ----
    {
      float a0 = 0, a1 = 0, a2 = 0, a3 = 0, a4 = 0, a5 = 0, a6 = 0, a7 = 0;
      {
        const float* scr = sc + ck * 16;
#pragma unroll
        for (int s5 = 0; s5 < 16; ++s5) {
          const bhalf8 v = *(const bhalf8*)(epL + (size_t)s5 * H_);
          const float wgt = scr[s5];
          a0 += wgt * (float)v[0];
          a1 += wgt * (float)v[1];
          a2 += wgt * (float)v[2];
          a3 += wgt * (float)v[3];
          a4 += wgt * (float)v[4];
          a5 += wgt * (float)v[5];
          a6 += wgt * (float)v[6];
          a7 += wgt * (float)v[7];
        }
      }
      {
        const float* scr = sc + 128 + ck * 26;
#pragma unroll 6
        for (int s5 = 0; s5 < 26; ++s5) {
          const bhalf8 v = *(const bhalf8*)(epC + (size_t)s5 * H_);
          const float wgt = scr[s5];
          a0 += wgt * (float)v[0];
          a1 += wgt * (float)v[1];
          a2 += wgt * (float)v[2];
          a3 += wgt * (float)v[3];
          a4 += wgt * (float)v[4];
          a5 += wgt * (float)v[5];
          a6 += wgt * (float)v[6];
          a7 += wgt * (float)v[7];
        }
      }
      float* pp = pC[ck][cg];
      pp[0] = a0; pp[1] = a1; pp[2] = a2; pp[3] = a3;
      pp[4] = a4; pp[5] = a5; pp[6] = a6; pp[7] = a7;
    }
    __syncthreads();                                        // (3)

    // ---- GRU: cL reduce (inv folded) + h-part BEFORE cL barrier ----
    float r0 = 0, r1 = 0, z0 = 0, z1 = 0, nh0 = 0, nh1 = 0, nx0 = 0, nx1 = 0;
    {
      const int gg = jj >> 3, j = jj & 7;
      float ssum = 0.0f;
#pragma unroll
      for (int c = 0; c < 8; ++c) ssum += pC[c][gg][j];
      cL[jj] = ssum * inv;
    }
#pragma unroll 4
    for (int k8 = 0; k8 < 32; ++k8) {          // h part (reads hc only)
      const bhalf* base = wbT + ((size_t)k8 * 768) * 8;
      const bhalf8 qR = *(const bhalf8*)(base + (size_t)jj * 8);
      const bhalf8 qZ = *(const bhalf8*)(base + (size_t)(256 + jj) * 8);
      const bhalf8 qN = *(const bhalf8*)(base + (size_t)(512 + jj) * 8);
      const float* v = hc + k8 * 8;
      r0 += (float)qR[0]*v[0] + (float)qR[2]*v[2] + (float)qR[4]*v[4] + (float)qR[6]*v[6];
      r1 += (float)qR[1]*v[1] + (float)qR[3]*v[3] + (float)qR[5]*v[5] + (float)qR[7]*v[7];
      z0 += (float)qZ[0]*v[0] + (float)qZ[2]*v[2] + (float)qZ[4]*v[4] + (float)qZ[6]*v[6];
      z1 += (float)qZ[1]*v[1] + (float)qZ[3]*v[3] + (float)qZ[5]*v[5] + (float)qZ[7]*v[7];
      nh0 += (float)qN[0]*v[0] + (float)qN[2]*v[2] + (float)qN[4]*v[4] + (float)qN[6]*v[6];
      nh1 += (float)qN[1]*v[1] + (float)qN[3]*v[3] + (float)qN[5]*v[5] + (float)qN[7]*v[7];
    }
    __syncthreads();                                        // (4) cL ready
#pragma unroll 4
    for (int k8 = 32; k8 < 64; ++k8) {         // c part
      const bhalf* base = wbT + ((size_t)k8 * 768) * 8;
      const bhalf8 qR = *(const bhalf8*)(base + (size_t)jj * 8);
      const bhalf8 qZ = *(const bhalf8*)(base + (size_t)(256 + jj) * 8);
      const bhalf8 qN = *(const bhalf8*)(base + (size_t)(512 + jj) * 8);
      const float* v = cL + (k8 - 32) * 8;
      r0 += (float)qR[0]*v[0] + (float)qR[2]*v[2] + (float)qR[4]*v[4] + (float)qR[6]*v[6];
      r1 += (float)qR[1]*v[1] + (float)qR[3]*v[3] + (float)qR[5]*v[5] + (float)qR[7]*v[7];
      z0 += (float)qZ[0]*v[0] + (float)qZ[2]*v[2] + (float)qZ[4]*v[4] + (float)qZ[6]*v[6];
      z1 += (float)qZ[1]*v[1] + (float)qZ[3]*v[3] + (float)qZ[5]*v[5] + (float)qZ[7]*v[7];
      nx0 += (float)qN[0]*v[0] + (float)qN[2]*v[2] + (float)qN[4]*v[4] + (float)qN[6]*v[6];
      nx1 += (float)qN[1]*v[1] + (float)qN[3]*v[3] + (float)qN[5]*v[5] + (float)qN[7]*v[7];
    }
    {
      const float sR = r0 + r1 + bRv;
      const float sZ = z0 + z1 + bZv;
      const float nh = nh0 + nh1 + bNhv;
      const float nx = nx0 + nx1 + bNxv;
      const float rr = 1.0f / (1.0f + __expf(-sR));
      const float zz = 1.0f / (1.0f + __expf(-sZ));
      const float nn = tanhf(nx + rr * nh);
      hn[jj] = (1.0f - zz) * nn + zz * hc[jj];   // ping-pong: no pre-barrier
    }
    __syncthreads();                                        // (5)

    // ---- out: 256 threads, 16-lane shuffle reduce, y feedback ----
    {
      const float* hv = hn + q_o * 16;
      float a0 = 0, a1 = 0, a2 = 0, a3 = 0;
#pragma unroll
      for (int jv = 0; jv < 4; ++jv) {
        const f32x4 h4 = *(const f32x4*)(hv + jv * 4);
        a0 += ow[jv][0] * h4[0]; a1 += ow[jv][1] * h4[1];
        a2 += ow[jv][2] * h4[2]; a3 += ow[jv][3] * h4[3];
      }
      float a = a0 + a1 + a2 + a3;
      a += __shfl_xor(a, 1, 64); a += __shfl_xor(a, 2, 64);
      a += __shfl_xor(a, 4, 64); a += __shfl_xor(a, 8, 64);
      if (q_o == 0) hn[256 + f_o] = a + outb_f;
    }
    __syncthreads();                                        // (6)
    if (tid < 16) {
      float v = hn[256 + tid] * linw_t;
      v += __shfl_xor(v, 1, 64); v += __shfl_xor(v, 2, 64);
      v += __shfl_xor(v, 4, 64); v += __shfl_xor(v, 8, 64);
      if (tid == 0) dout[(size_t)b * P_ + p] = v + linb0;
    }
  }
}

// ---------------------------------------------------------------------------
extern "C" void kernel_launch(void* const* d_in, const int* in_sizes, int n_in,
                              void* d_out, int out_size, void* d_ws, size_t ws_size,
                              hipStream_t stream)
{
  (void)in_sizes; (void)n_in; (void)out_size;
  const float* xb      = (const float*)d_in[0];
  const float* enc_Wih = (const float*)d_in[1];
  const float* enc_Whh = (const float*)d_in[2];
  const float* enc_bih = (const float*)d_in[3];
  const float* enc_bhh = (const float*)d_in[4];
  const float* att_W   = (const float*)d_in[5];
  const float* att_b   = (const float*)d_in[6];
  const float* dec_Wih = (const float*)d_in[7];
  const float* dec_Whh = (const float*)d_in[8];
  const float* dec_bih = (const float*)d_in[9];
  const float* dec_bhh = (const float*)d_in[10];
  const float* out_W   = (const float*)d_in[11];
  const float* out_b   = (const float*)d_in[12];
  const float* lin_W   = (const float*)d_in[13];
  const float* lin_b   = (const float*)d_in[14];
  float* dout = (float*)d_out;

  char* ws = (char*)d_ws;
  const size_t off_enc = 0;                                     // bf16 enc_out
  const size_t off_hp  = off_enc + (size_t)B_ * S_ * H_ * 2;    // 88,080,384
  const size_t off_hc  = off_hp + (size_t)2 * B_ * H_ * 4;      // hpack u32
  const size_t off_wb  = off_hc + (size_t)B_ * H_ * 4;
  const size_t off_ab  = off_wb + (size_t)64 * 768 * 8 * 2;
  const size_t off_fl  = off_ab + (size_t)36 * 336 * 8 * 2;
  const size_t need    = off_fl + 32 * 8 * sizeof(unsigned int);
  if (ws_size < need) return;

  bhalf* enc_out      = (bhalf*)(ws + off_enc);
  unsigned int* hpack = (unsigned int*)(ws + off_hp);
  float* hcur         = (float*)(ws + off_hc);
  bhalf* wbT          = (bhalf*)(ws + off_wb);
  bhalf* abT          = (bhalf*)(ws + off_ab);
  unsigned int* flags = (unsigned int*)(ws + off_fl);

  (void)hipMemsetAsync(flags, 0, 32 * 8 * sizeof(unsigned int), stream);
  wpack_kernel<<<(64 * 768 * 8 + 255) / 256, 256, 0, stream>>>(dec_Whh, dec_Wih, wbT);
  apack_kernel<<<(36 * 336 * 8 + 255) / 256, 256, 0, stream>>>(att_W, abT);
  enc_kernel<<<256, 128, 0, stream>>>(enc_Whh, enc_Wih, enc_bih, enc_bhh, xb,
                                      enc_out, hcur, hpack, flags);
  dec_kernel<<<B_, 256, 0, stream>>>(wbT, abT, att_b, dec_bih, dec_bhh,
                                     out_W, out_b, lin_W, lin_b,
                                     enc_out, hcur, xb, dout);
}